// Round 6
// baseline (863.873 us; speedup 1.0000x reference)
//
#include <hip/hip_runtime.h>
#include <hip/hip_fp16.h>

#define N_NODES 20000
#define N_EDGES 320000
#define DIM 256
// H=8 heads, C=32 channels/head

typedef _Float16 f16;
typedef unsigned int u32;
typedef f16 f16x8 __attribute__((ext_vector_type(8)));
typedef f16 f16x4 __attribute__((ext_vector_type(4)));
typedef float f32x4 __attribute__((ext_vector_type(4)));

#define GLL16(gsrc, ldst) __builtin_amdgcn_global_load_lds( \
    (const u32 __attribute__((address_space(1)))*)(gsrc),   \
    (u32 __attribute__((address_space(3)))*)(ldst), 16, 0, 0)

// ---- prep: 5 weights f32 (K x N) -> f16 transposed (N x K); pack biases; zero deg ----
__global__ void prep_all(const float* __restrict__ Wq, const float* __restrict__ Wk,
                         const float* __restrict__ Wv, const float* __restrict__ Ws,
                         const float* __restrict__ We,
                         const float* __restrict__ bq, const float* __restrict__ bk,
                         const float* __restrict__ bv, const float* __restrict__ bs,
                         f16* __restrict__ wtbase, float* __restrict__ biasAll,
                         int* __restrict__ deg) {
    if (blockIdx.x < 1280) {
        int gid = blockIdx.x * 256 + threadIdx.x;
        int w = gid >> 16;            // 0..4 : q,k,v,s,e
        int idx = gid & 65535;
        int k = idx >> 8, n = idx & 255;
        const float* W = (w == 0) ? Wq : (w == 1) ? Wk : (w == 2) ? Wv : (w == 3) ? Ws : We;
        wtbase[w * 65536 + n * 256 + k] = (f16)W[k * 256 + n];
    } else if (blockIdx.x < 1284) {
        int i = (blockIdx.x - 1280) * 256 + threadIdx.x;  // 0..1023
        int y = i >> 8, col = i & 255;
        const float* b = (y == 0) ? bq : (y == 1) ? bk : (y == 2) ? bv : bs;
        biasAll[i] = b[col];
    } else {
        int i = (blockIdx.x - 1284) * 256 + threadIdx.x;
        if (i < N_NODES) deg[i] = 0;
    }
}

// ---- GEMM v5: persistent, barrier-free steady state ----
// 512 blocks x 512 thr (8 waves). Per block: B half (128 cols x 256 K, 64 KB f16)
// staged into LDS ONCE (global_load_lds, pre-swizzled source), one __syncthreads,
// then loop over output tiles (128 rows x 128 cols) with NO barriers: per K-half
// (128), A loads for the next half are issued before this half's MFMAs, so every
// wave keeps ~4 KB in flight; 8-16 free-running waves/CU saturate HBM via TLP.
// Wave w owns rows [tile*128 + w*16, +16). LDS: row nrel x 32 slots of 16B,
// logical k-chunk kc at physical slot kc ^ (nrel&31) (write via swizzled global
// source, read with matching XOR) -> 2-way on ds_read_b128 (free, verified R4=0).
// EDGE=1: A = edge_attr read SEQUENTIALLY; C scatter-written to CSR slot
// slotOf[edge] (random 512B row writes merge to full lines in L2).
// EDGE=0: blockIdx>>6 = y: outSel=y>>1 (q,k,v,skip), colHalf=y&1.
template<int EDGE>
__global__ __launch_bounds__(512, 4) void gemm_v5(
    const float* __restrict__ A, const f16* __restrict__ WTbase,
    const float* __restrict__ biasAll, const int* __restrict__ slotOf,
    f16* __restrict__ outF16, float* __restrict__ outF32)
{
    __shared__ __align__(16) char lds[65536];
    const int tid = threadIdx.x;
    const int wave = tid >> 6, lane = tid & 63;
    const int l16 = lane & 15, lg = lane >> 4;

    int outSel, colHalf, x, xStride, tilesX, M;
    if (EDGE) {
        outSel = 4; colHalf = blockIdx.x & 1;
        x = blockIdx.x >> 1; xStride = 256; tilesX = N_EDGES / 128; M = N_EDGES;
    } else {
        const int y = blockIdx.x >> 6;
        outSel = y >> 1; colHalf = y & 1;
        x = blockIdx.x & 63; xStride = 64; tilesX = (N_NODES + 127) / 128; M = N_NODES;
    }
    const f16* __restrict__ WT = WTbase + outSel * 65536 + colHalf * (128 * 256);

    // ---- one-time B stage: 64 KB, pre-swizzled source, linear LDS dest ----
    {
        const int p = lane & 31;
#pragma unroll
        for (int r = 0; r < 8; ++r) {
            const int nrel = wave * 16 + r * 2 + (lane >> 5);
            const f16* src = WT + nrel * 256 + (p ^ (nrel & 31)) * 8;
            GLL16(src, &lds[(wave * 16 + r * 2) * 512]);
        }
    }

    float bias_[8];
    if (!EDGE) {
#pragma unroll
        for (int ct = 0; ct < 8; ++ct)
            bias_[ct] = biasAll[outSel * 256 + colHalf * 128 + ct * 16 + l16];
    }

    __syncthreads();   // B staged (drains the global_load_lds queue); only barrier

    f32x4 lo[4], hi[4];

#define ISSUE_A(ap_, h_) do {                                                  \
    _Pragma("unroll")                                                          \
    for (int ks_ = 0; ks_ < 4; ++ks_) {                                        \
        lo[ks_] = *(const f32x4*)((ap_) + (h_) * 128 + ks_ * 32 + lg * 8);     \
        hi[ks_] = *(const f32x4*)((ap_) + (h_) * 128 + ks_ * 32 + lg * 8 + 4); \
    } } while (0)

    // per-lane A row for tile x: row = x*128 + wave*16 + l16 (clamped for node)
    int row0 = x * 128 + wave * 16 + l16;
    if (!EDGE && row0 >= M) row0 = M - 1;
    const float* apCur = A + (size_t)row0 * DIM;
    ISSUE_A(apCur, 0);

    for (; x < tilesX; x += xStride) {
        const int rowBase = x * 128;
        f32x4 acc[8];
#pragma unroll
        for (int c = 0; c < 8; ++c) acc[c] = (f32x4){0.f, 0.f, 0.f, 0.f};

        // ---- half 0: convert (waits its loads), issue half-1 loads, MFMA ----
        f16x8 afr0[4];
#pragma unroll
        for (int ks = 0; ks < 4; ++ks) {
#pragma unroll
            for (int j = 0; j < 4; ++j) {
                afr0[ks][j]     = (f16)lo[ks][j];
                afr0[ks][4 + j] = (f16)hi[ks][j];
            }
        }
        ISSUE_A(apCur, 1);

        int srow[4];
        if (EDGE) {
#pragma unroll
            for (int i = 0; i < 4; ++i)
                srow[i] = slotOf[rowBase + wave * 16 + lg * 4 + i];
        }

#pragma unroll
        for (int ks = 0; ks < 4; ++ks) {
#pragma unroll
            for (int ct = 0; ct < 8; ++ct) {
                const int nrel = ct * 16 + l16;
                const int kc = ks * 4 + lg;
                f16x8 b = *(const f16x8*)(lds + nrel * 512 + ((kc ^ (nrel & 31)) * 16));
                acc[ct] = __builtin_amdgcn_mfma_f32_16x16x32_f16(afr0[ks], b, acc[ct], 0, 0, 0);
            }
        }

        // ---- half 1: convert, issue next tile's half-0 loads, MFMA ----
        f16x8 afr1[4];
#pragma unroll
        for (int ks = 0; ks < 4; ++ks) {
#pragma unroll
            for (int j = 0; j < 4; ++j) {
                afr1[ks][j]     = (f16)lo[ks][j];
                afr1[ks][4 + j] = (f16)hi[ks][j];
            }
        }
        {
            const int xn = x + xStride;
            int rowN = (xn < tilesX) ? (xn * 128 + wave * 16 + l16) : row0;
            if (!EDGE && rowN >= M) rowN = M - 1;
            const float* apNext = A + (size_t)rowN * DIM;
            ISSUE_A(apNext, 0);
            apCur = apNext;
            row0 = rowN;
        }

#pragma unroll
        for (int ks = 0; ks < 4; ++ks) {
#pragma unroll
            for (int ct = 0; ct < 8; ++ct) {
                const int nrel = ct * 16 + l16;
                const int kc = 16 + ks * 4 + lg;
                f16x8 b = *(const f16x8*)(lds + nrel * 512 + ((kc ^ (nrel & 31)) * 16));
                acc[ct] = __builtin_amdgcn_mfma_f32_16x16x32_f16(afr1[ks], b, acc[ct], 0, 0, 0);
            }
        }

        // ---- store tile: col = colHalf*128 + ct*16 + l16, row = rowBase+wave*16+lg*4+i
#pragma unroll
        for (int ct = 0; ct < 8; ++ct) {
            const int col = colHalf * 128 + ct * 16 + l16;
#pragma unroll
            for (int i = 0; i < 4; ++i) {
                const int row = rowBase + wave * 16 + lg * 4 + i;
                if (EDGE) {
                    outF16[(size_t)srow[i] * 256 + col] = (f16)acc[ct][i];
                } else if (row < M) {
                    const float val = acc[ct][i] + bias_[ct];
                    if (outSel < 3)
                        (outF16 + (size_t)outSel * N_NODES * 256)[(size_t)row * 256 + col] = (f16)val;
                    else
                        outF32[(size_t)row * 256 + col] = val;
                }
            }
        }
    }
#undef ISSUE_A
}

// ---- CSR build (by dst) ----
__global__ void count_deg(const int* __restrict__ dst, int* __restrict__ deg) {
    int e = blockIdx.x * blockDim.x + threadIdx.x;
    if (e < N_EDGES) atomicAdd(&deg[dst[e]], 1);
}

__global__ __launch_bounds__(1024) void scan_deg(const int* __restrict__ deg,
                                                 int* __restrict__ rowptr,
                                                 int* __restrict__ cursor) {
    __shared__ int part[1024];
    const int t = threadIdx.x;
    const int CH = (N_NODES + 1023) / 1024; // 20
    const int base = t * CH;
    int s = 0;
    for (int i = 0; i < CH; ++i) { int n = base + i; if (n < N_NODES) s += deg[n]; }
    part[t] = s;
    __syncthreads();
    for (int off = 1; off < 1024; off <<= 1) {
        int v = (t >= off) ? part[t - off] : 0;
        __syncthreads();
        part[t] += v;
        __syncthreads();
    }
    int run = (t == 0) ? 0 : part[t - 1];
    for (int i = 0; i < CH; ++i) {
        int n = base + i;
        if (n < N_NODES) { int dn = deg[n]; rowptr[n] = run; cursor[n] = run; run += dn; }
    }
    if (t == 1023) rowptr[N_NODES] = part[1023]; // == E
}

__global__ void scatter_edges(const int* __restrict__ src, const int* __restrict__ dst,
                              int* __restrict__ cursor,
                              int* __restrict__ slotOf, int* __restrict__ srcs) {
    int e = blockIdx.x * blockDim.x + threadIdx.x;
    if (e < N_EDGES) {
        int p = atomicAdd(&cursor[dst[e]], 1);
        slotOf[e] = p;        // edge id -> CSR slot (for edge-GEMM scatter store)
        srcs[p] = src[e];     // CSR-ordered source ids
    }
}

// ---- fused softmax + aggregate: one wave per dst node ----
// ef and srcs are CSR-ordered -> fully sequential; k/v gathers are L2/L3-resident.
// lane l handles channels [4l, 4l+4); head h = l/8 spans lanes [8h, 8h+8).
// Inner loop processes 4 edges per step with all 12 loads issued up front (one
// latency exposure per 4 edges instead of per edge).
__global__ __launch_bounds__(256) void aggregate(
    const f16* __restrict__ qf, const f16* __restrict__ kf, const f16* __restrict__ vf,
    const f16* __restrict__ ef, const int* __restrict__ srcs,
    const int* __restrict__ rowptr, float* __restrict__ out)
{
    const int wave = threadIdx.x >> 6;
    const int lane = threadIdx.x & 63;
    const int node = blockIdx.x * 4 + wave;
    if (node >= N_NODES) return;
    const int c0 = lane * 4;

    f32x4 qv;
    {
        f16x4 qh = *(const f16x4*)(qf + (size_t)node * 256 + c0);
        qv = (f32x4){(float)qh[0], (float)qh[1], (float)qh[2], (float)qh[3]};
    }
    float acc0 = 0.f, acc1 = 0.f, acc2 = 0.f, acc3 = 0.f, den = 0.f;
    const int beg = rowptr[node], end = rowptr[node + 1];

#define BODY(eh, kh, vh) {                                                      \
        const float _e0 = (float)(eh)[0], _e1 = (float)(eh)[1];                 \
        const float _e2 = (float)(eh)[2], _e3 = (float)(eh)[3];                 \
        float _d = qv[0] * ((float)(kh)[0] + _e0) + qv[1] * ((float)(kh)[1] + _e1) \
                 + qv[2] * ((float)(kh)[2] + _e2) + qv[3] * ((float)(kh)[3] + _e3); \
        _d += __shfl_xor(_d, 1);                                                \
        _d += __shfl_xor(_d, 2);                                                \
        _d += __shfl_xor(_d, 4);                                                \
        const float _w = __expf(_d * 0.1767766952966369f);                      \
        den += _w;                                                              \
        acc0 += _w * ((float)(vh)[0] + _e0);                                    \
        acc1 += _w * ((float)(vh)[1] + _e1);                                    \
        acc2 += _w * ((float)(vh)[2] + _e2);                                    \
        acc3 += _w * ((float)(vh)[3] + _e3);                                    \
    }

    int idx = beg;
    for (; idx + 4 <= end; idx += 4) {
        const int s0 = srcs[idx], s1 = srcs[idx + 1], s2 = srcs[idx + 2], s3 = srcs[idx + 3];
        f16x4 ea0 = *(const f16x4*)(ef + (size_t)(idx + 0) * 256 + c0);
        f16x4 ea1 = *(const f16x4*)(ef + (size_t)(idx + 1) * 256 + c0);
        f16x4 ea2 = *(const f16x4*)(ef + (size_t)(idx + 2) * 256 + c0);
        f16x4 ea3 = *(const f16x4*)(ef + (size_t)(idx + 3) * 256 + c0);
        f16x4 ka0 = *(const f16x4*)(kf + (size_t)s0 * 256 + c0);
        f16x4 ka1 = *(const f16x4*)(kf + (size_t)s1 * 256 + c0);
        f16x4 ka2 = *(const f16x4*)(kf + (size_t)s2 * 256 + c0);
        f16x4 ka3 = *(const f16x4*)(kf + (size_t)s3 * 256 + c0);
        f16x4 va0 = *(const f16x4*)(vf + (size_t)s0 * 256 + c0);
        f16x4 va1 = *(const f16x4*)(vf + (size_t)s1 * 256 + c0);
        f16x4 va2 = *(const f16x4*)(vf + (size_t)s2 * 256 + c0);
        f16x4 va3 = *(const f16x4*)(vf + (size_t)s3 * 256 + c0);
        BODY(ea0, ka0, va0); BODY(ea1, ka1, va1); BODY(ea2, ka2, va2); BODY(ea3, ka3, va3);
    }
    for (; idx < end; ++idx) {
        const int s = srcs[idx];
        f16x4 eh1 = *(const f16x4*)(ef + (size_t)idx * 256 + c0);
        f16x4 kh1 = *(const f16x4*)(kf + (size_t)s * 256 + c0);
        f16x4 vh1 = *(const f16x4*)(vf + (size_t)s * 256 + c0);
        BODY(eh1, kh1, vh1);
    }
#undef BODY

    const float inv = 1.0f / (den + 1e-16f);
    const size_t ob = (size_t)node * 256 + c0;
    f32x4 o = *(f32x4*)(out + ob);              // holds skip from gemm_v5 outSel==3
    o[0] += acc0 * inv; o[1] += acc1 * inv; o[2] += acc2 * inv; o[3] += acc3 * inv;
    *(f32x4*)(out + ob) = o;
}

extern "C" void kernel_launch(void* const* d_in, const int* in_sizes, int n_in,
                              void* d_out, int out_size, void* d_ws, size_t ws_size,
                              hipStream_t stream) {
    const float* x   = (const float*)d_in[0];
    const int*   ei  = (const int*)d_in[1];     // [0..E): src, [E..2E): dst
    const float* ea  = (const float*)d_in[2];
    const float* Wq  = (const float*)d_in[3];
    const float* bq  = (const float*)d_in[4];
    const float* Wk  = (const float*)d_in[5];
    const float* bk  = (const float*)d_in[6];
    const float* Wv  = (const float*)d_in[7];
    const float* bv  = (const float*)d_in[8];
    const float* We  = (const float*)d_in[9];
    const float* Ws  = (const float*)d_in[10];
    const float* bs  = (const float*)d_in[11];
    float* out = (float*)d_out;

    const int* srcArr = ei;
    const int* dstArr = ei + N_EDGES;

    // workspace layout
    char* w = (char*)d_ws;
    size_t off = 0;
    f16* wtbase = (f16*)(w + off); off += 5 * 65536 * 2;            // q,k,v,s,e transposed
    f16* qf = (f16*)(w + off); off += (size_t)N_NODES * 256 * 2;
    f16* kf = (f16*)(w + off); off += (size_t)N_NODES * 256 * 2;
    f16* vf = (f16*)(w + off); off += (size_t)N_NODES * 256 * 2;
    f16* ef = (f16*)(w + off); off += (size_t)N_EDGES * 256 * 2;    // CSR-slot order
    int* deg    = (int*)(w + off); off += 80016;
    int* rowptr = (int*)(w + off); off += 80016;
    int* cursor = (int*)(w + off); off += 80016;
    int* slotOf = (int*)(w + off); off += (size_t)N_EDGES * 4;      // edge id -> CSR slot
    int* srcs   = (int*)(w + off); off += (size_t)N_EDGES * 4;      // CSR-slot order
    float* biasAll = (float*)(w + off); off += 4 * 256 * 4;
    (void)ws_size; (void)n_in; (void)in_sizes; (void)out_size;

    // prep: weight transpose + bias pack + deg zero (one launch)
    prep_all<<<1284 + (N_NODES + 255) / 256, 256, 0, stream>>>(
        Wq, Wk, Wv, Ws, We, bq, bk, bv, bs, wtbase, biasAll, deg);

    // CSR build (edge GEMM consumes slotOf for its scatter store)
    count_deg<<<(N_EDGES + 255) / 256, 256, 0, stream>>>(dstArr, deg);
    scan_deg<<<1, 1024, 0, stream>>>(deg, rowptr, cursor);
    scatter_edges<<<(N_EDGES + 255) / 256, 256, 0, stream>>>(srcArr, dstArr, cursor, slotOf, srcs);

    // persistent GEMMs: node (512 blocks: 8 y-groups x 64) + edge (512 blocks: 2 halves x 256)
    gemm_v5<0><<<512, 512, 0, stream>>>(x, wtbase, biasAll, nullptr, qf, out);
    gemm_v5<1><<<512, 512, 0, stream>>>(ea, wtbase, nullptr, slotOf, ef, nullptr);

    // fused softmax + aggregation, one wave per node
    aggregate<<<N_NODES / 4, 256, 0, stream>>>(qf, kf, vf, ef, srcs, rowptr, out);
}